// Round 12
// baseline (61.201 us; speedup 1.0000x reference)
//
#include <hip/hip_runtime.h>
#include <hip/hip_bf16.h>

// GQA paged-prefill attention, MI355X gfx950.
// Causal mask j<=i over concat(past,new) => only first Q_LEN (=1024) gathered
// past tokens are live. Flash-attention over tokens 0..1023 of paged cache.
//
// R12: swapped-QK 32x32 structure (m214-style), in-register softmax.
//  - wave owns 32 q-rows of one head; mfma_f32_32x32x16_bf16.
//  - QK computed as mfma(K, Q) -> S[tok][q], q in lane dim: lane holds 32
//    P-values of ONE q-row -> softmax fully in-register (31 fmax + 1 shfl).
//  - P -> bf16 A-frags via packed pairs + 4 shfl_xor + cndmask (no P LDS).
//  - block = 4 waves = 4 GQA heads sharing K/V^T LDS dbuf (64KB, 2 blk/CU).
//  - kv-split x2 (uniform combine), grid 512, max 8 tiles/block.

#define Q_STRIDE 4096
#define SCALE 0.08838834764831845f
#define RESCALE_THR 8.0f
#define KSW_TILE 16384                     // bytes per (hkv, 64-tok tile)
#define VSW_OFF  (2 * 1024 * 1024)         // V^T tiles at +2MB
#define ACC1_OFF (4 * 1024 * 1024)         // half1 acc bf16: 32768 rows x 256B
#define ML0_OFF  (ACC1_OFF + 32768 * 256)  // half0 (m,l): 32768 x 8B
#define ML1_OFF  (ML0_OFF + 32768 * 8)     // half1 (m,l): 32768 x 8B

typedef short short8 __attribute__((ext_vector_type(8)));
typedef float f32x16 __attribute__((ext_vector_type(16)));
typedef unsigned int uint_t;
typedef uint_t u32x4 __attribute__((ext_vector_type(4)));
typedef unsigned short ushort_t;

__device__ __forceinline__ ushort_t f2bf(float f) {
    return __builtin_bit_cast(ushort_t, __float2bfloat16(f));
}
__device__ __forceinline__ uint_t pk2(float a, float b) {
    return (uint_t)f2bf(a) | ((uint_t)f2bf(b) << 16);
}
__device__ __forceinline__ float bf2f(ushort_t u) {
    uint_t x = ((uint_t)u) << 16;
    return __builtin_bit_cast(float, x);
}

// ---------------- prep: paged fp32 -> dense swizzled bf16 ----------------
__launch_bounds__(256)
__global__ void prep_kv(const float* __restrict__ kvc,
                        const int* __restrict__ bt,
                        char* __restrict__ wsb)
{
    __shared__ float sVt[64 * 128];
    const int blk = blockIdx.x;        // 128 blocks = hkv(8) x jb(16)
    const int hkv = blk >> 4;
    const int jb  = blk & 15;
    const int tid = threadIdx.x;
    char* kout = wsb + (size_t)(hkv * 16 + jb) * KSW_TILE;
    char* vout = wsb + VSW_OFF + (size_t)(hkv * 16 + jb) * KSW_TILE;

    // K: [t 64][d 128] bf16; 16B chunk c stored at slot c^(t&15)
#pragma unroll
    for (int i = 0; i < 4; ++i) {
        const int u = tid + i * 256;   // t(64) x c(16)
        const int t = u >> 4, c = u & 15;
        const int gtok = jb * 64 + t;
        const int page = bt[gtok >> 4];
        const float* src = kvc + (size_t)page * 32768 + (size_t)hkv * 2048
                         + (gtok & 15) * 128 + c * 8;
        float4 a = *(const float4*)src;
        float4 b = *(const float4*)(src + 4);
        uint4 p;
        p.x = pk2(a.x, a.y); p.y = pk2(a.z, a.w);
        p.z = pk2(b.x, b.y); p.w = pk2(b.z, b.w);
        *(uint4*)(kout + t * 256 + ((c ^ (t & 15)) << 4)) = p;
    }
    // V: coalesced fp32 read -> LDS ([t][d])
#pragma unroll
    for (int i = 0; i < 8; ++i) {
        const int u = tid + i * 256;   // t(64) x c4(32)
        const int t = u >> 5, c4 = u & 31;
        const int gtok = jb * 64 + t;
        const int page = bt[gtok >> 4];
        const float* src = kvc + (size_t)page * 32768 + 16384
                         + (size_t)hkv * 2048 + (gtok & 15) * 128 + c4 * 4;
        *(float4*)(sVt + t * 128 + c4 * 4) = *(const float4*)src;
    }
    __syncthreads();
    // V^T: [d 128][t 64] bf16; 16B chunk ch (8 toks) stored at slot ch^(d&7)
#pragma unroll
    for (int i = 0; i < 4; ++i) {
        const int u = tid + i * 256;   // d(128) x ch(8)
        const int d = u >> 3, ch = u & 7;
        float v[8];
#pragma unroll
        for (int k = 0; k < 8; ++k) v[k] = sVt[(8 * ch + k) * 128 + d];
        uint4 p;
        p.x = pk2(v[0], v[1]); p.y = pk2(v[2], v[3]);
        p.z = pk2(v[4], v[5]); p.w = pk2(v[6], v[7]);
        *(uint4*)(vout + d * 128 + ((ch ^ (d & 7)) << 4)) = p;
    }
}

// ---------------- main attention ----------------
#define GLL16(G, L) __builtin_amdgcn_global_load_lds(                         \
    (const uint_t __attribute__((address_space(1)))*)(G),                     \
    (uint_t __attribute__((address_space(3)))*)(L), 16, 0, 0)

// Stage tile JB (16KB K + 16KB V^T); wave w covers bytes [w*4K, +4K).
#define STAGE(JB, KB, VB) {                                                   \
    const char* b_ = kvbf + (size_t)(hkv * 16 + (JB)) * KSW_TILE              \
                   + w * 4096 + lane * 16;                                    \
    GLL16(b_,                  (KB) + w * 4096);                              \
    GLL16(b_ + 1024,           (KB) + w * 4096 + 1024);                       \
    GLL16(b_ + 2048,           (KB) + w * 4096 + 2048);                       \
    GLL16(b_ + 3072,           (KB) + w * 4096 + 3072);                       \
    GLL16(b_ + VSW_OFF,        (VB) + w * 4096);                              \
    GLL16(b_ + VSW_OFF + 1024, (VB) + w * 4096 + 1024);                       \
    GLL16(b_ + VSW_OFF + 2048, (VB) + w * 4096 + 2048);                       \
    GLL16(b_ + VSW_OFF + 3072, (VB) + w * 4096 + 3072);                       \
}

__launch_bounds__(256)
__global__ void attn_main(const float* __restrict__ q,
                          const char* __restrict__ kvbf,
                          float* __restrict__ out,
                          char* __restrict__ wsb)
{
    __shared__ __align__(16) char sK[2][16384];
    __shared__ __align__(16) char sV[2][16384];

    const int bid  = blockIdx.x;       // 512 = half(2) x hkv(8) x rt(32)
    const int half = bid >> 8;
    const int r8   = bid & 255;
    const int hkv  = r8 >> 5;
    const int rt   = r8 & 31;          // 32-row tile index
    const int nt   = (rt >> 1) + 1;    // kv tiles covering rows 32rt..32rt+31
    const int nt0  = (nt + 1) >> 1;
    const int jb0  = half ? nt0 : 0;
    const int jb1  = half ? nt : nt0;
    const int tid  = threadIdx.x;
    const int w    = tid >> 6;         // wave = GQA head offset
    const int lane = tid & 63;
    const int l31  = lane & 31;        // q-col within 32-row tile
    const int hi   = lane >> 5;
    const int hi4  = hi * 4;
    const int h    = hkv * 4 + w;

    // ---- Q fragments (SCALE folded) as B-operand:
    //  lane holds Q[q = rt*32 + l31][d = ks*16 + hi*8 + e], ks 0..7
    short8 qf[8];
    {
        const float* qp = q + (size_t)(rt * 32 + l31) * Q_STRIDE + h * 128;
#pragma unroll
        for (int ks = 0; ks < 8; ++ks) {
            const int d0 = ks * 16 + hi * 8;
            float4 a = *(const float4*)(qp + d0);
            float4 b = *(const float4*)(qp + d0 + 4);
            short8 v;
            v[0] = (short)f2bf(a.x * SCALE); v[1] = (short)f2bf(a.y * SCALE);
            v[2] = (short)f2bf(a.z * SCALE); v[3] = (short)f2bf(a.w * SCALE);
            v[4] = (short)f2bf(b.x * SCALE); v[5] = (short)f2bf(b.y * SCALE);
            v[6] = (short)f2bf(b.z * SCALE); v[7] = (short)f2bf(b.w * SCALE);
            qf[ks] = v;
        }
    }

    f32x16 acc[4];                     // O[q=reg][d = db*32 + l31]
#pragma unroll
    for (int db = 0; db < 4; ++db)
#pragma unroll
        for (int r = 0; r < 16; ++r) acc[db][r] = 0.f;
    float m_run  = -1e30f;             // per-lane: q = l31
    float l_part = 0.f;                // per-lane partial (own 32 toks/tile)

    if (jb0 < jb1) {
        STAGE(jb0, sK[0], sV[0])
    }
    __syncthreads();

    for (int jb = jb0; jb < jb1; ++jb) {
        const int cur = (jb - jb0) & 1;
        const char* kbuf = sK[cur];
        const char* vbuf = sV[cur];
        const bool pf = (jb + 1 < jb1);
        if (pf) {
            STAGE(jb + 1, sK[cur ^ 1], sV[cur ^ 1])
        }

        // ---- S^T = K Q^T : sacc[hf][reg] = S[tok][q=l31]
        f32x16 s0, s1;
#pragma unroll
        for (int r = 0; r < 16; ++r) { s0[r] = 0.f; s1[r] = 0.f; }
        __builtin_amdgcn_s_setprio(1);
#pragma unroll
        for (int ks = 0; ks < 8; ++ks) {
            const uint_t c0 = (uint_t)(((ks * 2 + hi) ^ (l31 & 15)) << 4);
            short8 ka0 = *(const short8*)(kbuf + l31 * 256 + c0);
            short8 ka1 = *(const short8*)(kbuf + 8192 + l31 * 256 + c0);
            s0 = __builtin_amdgcn_mfma_f32_32x32x16_bf16(ka0, qf[ks], s0, 0, 0, 0);
            s1 = __builtin_amdgcn_mfma_f32_32x32x16_bf16(ka1, qf[ks], s1, 0, 0, 0);
        }
        __builtin_amdgcn_s_setprio(0);

        // ---- causal mask (diagonal tile only); tok base of tri-half == row base
        const bool diag = (jb == nt - 1);
        if (diag) {
            if (rt & 1) {
#pragma unroll
                for (int r = 0; r < 16; ++r) {
                    const int treg = (r & 3) + 8 * (r >> 2) + hi4;
                    if (treg > l31) s1[r] = -1e30f;
                }
            } else {
#pragma unroll
                for (int r = 0; r < 16; ++r) {
                    const int treg = (r & 3) + 8 * (r >> 2) + hi4;
                    if (treg > l31) s0[r] = -1e30f;
                    s1[r] = -1e30f;
                }
            }
        }

        // ---- in-register softmax with deferred max
        float pm = s0[0];
#pragma unroll
        for (int r = 1; r < 16; ++r) pm = fmaxf(pm, s0[r]);
#pragma unroll
        for (int r = 0; r < 16; ++r) pm = fmaxf(pm, s1[r]);
        const float rmax = fmaxf(pm, __shfl_xor(pm, 32));
        if (__any(rmax > m_run + RESCALE_THR)) {
            const float mn = fmaxf(m_run, rmax);
            const float al = __expf(m_run - mn);
            m_run = mn;
            l_part *= al;
#pragma unroll
            for (int r = 0; r < 16; ++r) {
                const float ar = __shfl(al, (r & 3) + 8 * (r >> 2) + hi4);
#pragma unroll
                for (int db = 0; db < 4; ++db) acc[db][r] *= ar;
            }
        }
        float ls = 0.f;
#pragma unroll
        for (int r = 0; r < 16; ++r) {
            float e0 = __expf(s0[r] - m_run);
            float e1 = __expf(s1[r] - m_run);
            s0[r] = e0; s1[r] = e1;
            ls += e0 + e1;
        }
        l_part += ls;

        // ---- P -> bf16 A-fragments in-register (per hf: pack + 4 shfl)
        short8 pa[4];
#pragma unroll
        for (int hf = 0; hf < 2; ++hf) {
            const f32x16& s = hf ? s1 : s0;
            uint_t w0 = pk2(s[0],  s[1]),  w1 = pk2(s[2],  s[3]);
            uint_t w2 = pk2(s[4],  s[5]),  w3 = pk2(s[6],  s[7]);
            uint_t w4 = pk2(s[8],  s[9]),  w5 = pk2(s[10], s[11]);
            uint_t w6 = pk2(s[12], s[13]), w7 = pk2(s[14], s[15]);
            const uint_t sA = __shfl_xor(hi ? w0 : w2, 32);
            const uint_t sB = __shfl_xor(hi ? w1 : w3, 32);
            const uint_t sC = __shfl_xor(hi ? w4 : w6, 32);
            const uint_t sD = __shfl_xor(hi ? w5 : w7, 32);
            u32x4 f0, f1;
            f0[0] = hi ? sA : w0; f0[1] = hi ? sB : w1;
            f0[2] = hi ? w2 : sA; f0[3] = hi ? w3 : sB;
            f1[0] = hi ? sC : w4; f1[1] = hi ? sD : w5;
            f1[2] = hi ? w6 : sC; f1[3] = hi ? w7 : sD;
            pa[hf * 2]     = __builtin_bit_cast(short8, f0);
            pa[hf * 2 + 1] = __builtin_bit_cast(short8, f1);
        }

        // ---- O += P V  (B = V^T fragments from LDS)
        __builtin_amdgcn_s_setprio(1);
#pragma unroll
        for (int kf = 0; kf < 4; ++kf) {         // kf = hf*2 + ks2
#pragma unroll
            for (int db = 0; db < 4; ++db) {
                const uint_t byte = (uint_t)(db * 4096 + l31 * 128)
                    + (uint_t)((((kf << 1) + hi) ^ (l31 & 7)) << 4);
                short8 vb = *(const short8*)(vbuf + byte);
                acc[db] = __builtin_amdgcn_mfma_f32_32x32x16_bf16(pa[kf], vb, acc[db], 0, 0, 0);
            }
        }
        __builtin_amdgcn_s_setprio(0);

        if (pf) __syncthreads();
    }

    // ---- epilogue: emit partials (normalization deferred to combine)
    const float l_row = l_part + __shfl_xor(l_part, 32);
    if (half == 0) {
#pragma unroll
        for (int db = 0; db < 4; ++db)
#pragma unroll
            for (int r = 0; r < 16; ++r) {
                const int qg = rt * 32 + (r & 3) + 8 * (r >> 2) + hi4;
                out[(size_t)qg * Q_STRIDE + h * 128 + db * 32 + l31] = acc[db][r];
            }
        if (lane < 32) {
            float* ml = (float*)(wsb + ML0_OFF) + (size_t)(h * 1024 + rt * 32 + l31) * 2;
            ml[0] = m_run; ml[1] = l_row;
        }
    } else {
        ushort_t* a1b = (ushort_t*)(wsb + ACC1_OFF);
#pragma unroll
        for (int db = 0; db < 4; ++db)
#pragma unroll
            for (int r = 0; r < 16; ++r) {
                const int qg = rt * 32 + (r & 3) + 8 * (r >> 2) + hi4;
                a1b[(size_t)(h * 1024 + qg) * 128 + db * 32 + l31] = f2bf(acc[db][r]);
            }
        if (lane < 32) {
            float* ml = (float*)(wsb + ML1_OFF) + (size_t)(h * 1024 + rt * 32 + l31) * 2;
            ml[0] = m_run; ml[1] = l_row;
        }
    }
}

// ---------------- combine (all rows) ----------------
__launch_bounds__(256)
__global__ void attn_combine(float* __restrict__ out, const char* __restrict__ wsb)
{
    const int pid = blockIdx.x;           // 512 = h(32) x qblk(16)
    const int h   = pid >> 4;
    const int qb  = (pid & 15) * 64;
    const int tid = threadIdx.x;
    const int d4  = (tid & 31) * 4;
    const float* ml0b = (const float*)(wsb + ML0_OFF);
    const float* ml1b = (const float*)(wsb + ML1_OFF);
    const ushort_t* a1b = (const ushort_t*)(wsb + ACC1_OFF);

#pragma unroll
    for (int p = 0; p < 8; ++p) {
        const int r = (tid >> 5) + p * 8;            // row 0..63
        const size_t idx = (size_t)h * 1024 + qb + r;
        const float m1 = ml0b[idx * 2], l1 = ml0b[idx * 2 + 1];
        const float m2 = ml1b[idx * 2], l2 = ml1b[idx * 2 + 1];
        const float m  = fmaxf(m1, m2);
        const float a1 = __expf(m1 - m), a2 = __expf(m2 - m);
        const float inv = 1.0f / (l1 * a1 + l2 * a2);
        float* o = out + (size_t)(qb + r) * Q_STRIDE + h * 128 + d4;
        const ushort_t* y4 = a1b + idx * 128 + d4;
        float4 x = *(const float4*)o;
        x.x = (x.x * a1 + bf2f(y4[0]) * a2) * inv;
        x.y = (x.y * a1 + bf2f(y4[1]) * a2) * inv;
        x.z = (x.z * a1 + bf2f(y4[2]) * a2) * inv;
        x.w = (x.w * a1 + bf2f(y4[3]) * a2) * inv;
        *(float4*)o = x;
    }
}

extern "C" void kernel_launch(void* const* d_in, const int* in_sizes, int n_in,
                              void* d_out, int out_size, void* d_ws, size_t ws_size,
                              hipStream_t stream) {
    const float* q   = (const float*)d_in[0];
    // d_in[1] (k) and d_in[2] (v) are dead under the reference's causal mask.
    const float* kvc = (const float*)d_in[3];
    const int*   bt  = (const int*)d_in[4];
    float* out = (float*)d_out;
    char*  wsb = (char*)d_ws;
    prep_kv<<<dim3(128), dim3(256), 0, stream>>>(kvc, bt, wsb);
    attn_main<<<dim3(512), dim3(256), 0, stream>>>(q, wsb, out, wsb);
    attn_combine<<<dim3(512), dim3(256), 0, stream>>>(out, wsb);
}

// Round 13
// 45.749 us; speedup vs baseline: 1.3377x; 1.3377x over previous
//
#include <hip/hip_runtime.h>
#include <hip/hip_bf16.h>

// GQA paged-prefill attention, MI355X gfx950.
// Causal mask j<=i over concat(past,new) => only first Q_LEN (=1024) gathered
// past tokens are live. Flash-attention over tokens 0..1023 of paged cache.
//
// R13 = R6 (best main kernel) with ONE change: counted-vmcnt pipeline (T4).
// Per tile: STAGE(j+1); s_waitcnt vmcnt(8) [tile-j landed, j+1 stays IN
// FLIGHT]; s_barrier; compute; s_barrier. Replaces __syncthreads()'s
// vmcnt(0) full drain that serialized every tile on prefetch completion.

#define NUM_HEADS 32
#define HEAD_DIM 128
#define Q_STRIDE 4096
#define SCALE 0.08838834764831845f
#define RESCALE_THR 8.0f
#define KSW_TILE 16384                 // bytes per (hkv, jb) tile
#define VSW_OFF (2 * 1024 * 1024)      // Vt tiles start 2MB into ws

typedef short short8 __attribute__((ext_vector_type(8)));
typedef float f32x4 __attribute__((ext_vector_type(4)));
typedef unsigned short ushort_t;
typedef unsigned int uint_t;

__device__ __forceinline__ ushort_t f2bf(float f) {
    return __builtin_bit_cast(ushort_t, __float2bfloat16(f));
}
__device__ __forceinline__ uint_t pk2(float a, float b) {
    return (uint_t)f2bf(a) | ((uint_t)f2bf(b) << 16);
}

// ---------------- prep: paged fp32 -> dense swizzled bf16 ----------------
__launch_bounds__(256)
__global__ void prep_kv(const float* __restrict__ kvc,
                        const int* __restrict__ bt,
                        char* __restrict__ wsb)
{
    __shared__ float sVt[64 * 128];
    const int blk = blockIdx.x;        // 128 blocks = hkv(8) x jb(16)
    const int hkv = blk >> 4;
    const int jb  = blk & 15;
    const int tid = threadIdx.x;
    char* kout = wsb + (size_t)(hkv * 16 + jb) * KSW_TILE;
    char* vout = wsb + VSW_OFF + (size_t)(hkv * 16 + jb) * KSW_TILE;

    // K: [t 64][d 128] bf16, 16B chunk c at byte t*256 + ((c*16)^((t&7)<<4))
#pragma unroll
    for (int i = 0; i < 4; ++i) {
        const int u = tid + i * 256;   // t(64) x c(16)
        const int t = u >> 4, c = u & 15;
        const int gtok = jb * 64 + t;
        const int page = bt[gtok >> 4];
        const float* src = kvc + (size_t)page * 32768 + (size_t)hkv * 2048
                         + (gtok & 15) * 128 + c * 8;
        float4 a = *(const float4*)src;
        float4 b = *(const float4*)(src + 4);
        uint4 p;
        p.x = pk2(a.x, a.y); p.y = pk2(a.z, a.w);
        p.z = pk2(b.x, b.y); p.w = pk2(b.z, b.w);
        *(uint4*)(kout + t * 256 + ((c * 16) ^ ((t & 7) << 4))) = p;
    }
    // V: coalesced fp32 read -> LDS
#pragma unroll
    for (int i = 0; i < 8; ++i) {
        const int u = tid + i * 256;   // t(64) x c4(32)
        const int t = u >> 5, c4 = u & 31;
        const int gtok = jb * 64 + t;
        const int page = bt[gtok >> 4];
        const float* src = kvc + (size_t)page * 32768 + 16384
                         + (size_t)hkv * 2048 + (gtok & 15) * 128 + c4 * 4;
        *(float4*)(sVt + t * 128 + c4 * 4) = *(const float4*)src;
    }
    __syncthreads();
    // Vt: [d 128][t 64] bf16, 16B chunk ch at byte (d*128+16*ch)^((d&7)<<4)
#pragma unroll
    for (int i = 0; i < 4; ++i) {
        const int u = tid + i * 256;   // d(128) x ch(8)
        const int d = u >> 3, ch = u & 7;
        float v[8];
#pragma unroll
        for (int k = 0; k < 8; ++k) v[k] = sVt[(8 * ch + k) * 128 + d];
        uint4 p;
        p.x = pk2(v[0], v[1]); p.y = pk2(v[2], v[3]);
        p.z = pk2(v[4], v[5]); p.w = pk2(v[6], v[7]);
        *(uint4*)(vout + ((d * 128 + 16 * ch) ^ ((d & 7) << 4))) = p;
    }
}

// ---------------- main attention ----------------
#define GLL16(G, L) __builtin_amdgcn_global_load_lds(                         \
    (const uint_t __attribute__((address_space(1)))*)(G),                     \
    (uint_t __attribute__((address_space(3)))*)(L), 16, 0, 0)

// Stage tile JB: 8 gll per wave (4KB K slice + 4KB V slice).
#define STAGE(JB, KB, VB) {                                                   \
    const char* ks = kvbf + (size_t)(hkv * 16 + (JB)) * KSW_TILE              \
                   + w * 4096 + lane * 16;                                    \
    const char* vs = ks + VSW_OFF;                                            \
    _Pragma("unroll")                                                         \
    for (int i = 0; i < 4; ++i) {                                             \
        GLL16(ks + i * 1024, (KB) + w * 4096 + i * 1024);                     \
        GLL16(vs + i * 1024, (VB) + w * 4096 + i * 1024);                     \
    }                                                                         \
}

__launch_bounds__(256)
__global__ void attn_main(const float* __restrict__ q,
                          const char* __restrict__ kvbf,
                          float* __restrict__ out)
{
    __shared__ __align__(16) char sK[2][16384];
    __shared__ __align__(16) char sV[2][16384];
    __shared__ __align__(16) char sP[4][2048];

    const int bid = blockIdx.x;
    const int h   = bid & 31;
    const int qt  = 15 - (bid >> 5);   // long blocks first
    const int hkv = h >> 2;
    const int tid  = threadIdx.x;
    const int w    = tid >> 6;
    const int lane = tid & 63;
    const int l15  = lane & 15;
    const int lhi  = lane >> 4;

    // ---- Q fragments (SCALE folded): wave w owns rows qt*64 + w*16 + l15
    short8 qf[4];
    {
        const int qrow = qt * 64 + w * 16 + l15;
        const float* qp = q + (size_t)qrow * Q_STRIDE + h * HEAD_DIM;
#pragma unroll
        for (int s = 0; s < 4; ++s) {
            const int d0 = s * 32 + lhi * 8;
            float4 a = *(const float4*)(qp + d0);
            float4 b = *(const float4*)(qp + d0 + 4);
            short8 v;
            v[0] = (short)f2bf(a.x * SCALE); v[1] = (short)f2bf(a.y * SCALE);
            v[2] = (short)f2bf(a.z * SCALE); v[3] = (short)f2bf(a.w * SCALE);
            v[4] = (short)f2bf(b.x * SCALE); v[5] = (short)f2bf(b.y * SCALE);
            v[6] = (short)f2bf(b.z * SCALE); v[7] = (short)f2bf(b.w * SCALE);
            qf[s] = v;
        }
    }

    f32x4 acc[8];
#pragma unroll
    for (int n2 = 0; n2 < 8; ++n2) acc[n2] = (f32x4){0.f, 0.f, 0.f, 0.f};
    float m_run[4]  = {-1e30f, -1e30f, -1e30f, -1e30f};
    float l_part[4] = {0.f, 0.f, 0.f, 0.f};

    // prologue: tile 0 -> buf 0, full drain once
    STAGE(0, sK[0], sV[0])
    __syncthreads();

    for (int jb = 0; jb <= qt; ++jb) {
        const int cur = jb & 1;
        char* kbuf = sK[cur];
        char* vbuf = sV[cur];
        const bool pf = (jb < qt);
        if (pf) {
            // issue tile j+1 (overwrites buf read at iter j-1; safe: trailing
            // barrier of iter j-1 already passed)
            STAGE(jb + 1, sK[cur ^ 1], sV[cur ^ 1])
            // wait ONLY for tile-j's 8 gll (issued last iter); the 8 newest
            // (tile j+1) stay in flight across the barrier  [T4]
            asm volatile("s_waitcnt vmcnt(8)" ::: "memory");
        } else {
            asm volatile("s_waitcnt vmcnt(0)" ::: "memory");
        }
        __builtin_amdgcn_sched_barrier(0);
        __builtin_amdgcn_s_barrier();      // everyone's tile-j data in LDS
        __builtin_amdgcn_sched_barrier(0);

        // ---- S = Q K^T
        f32x4 sacc[4];
#pragma unroll
        for (int n = 0; n < 4; ++n) sacc[n] = (f32x4){0.f, 0.f, 0.f, 0.f};
#pragma unroll
        for (int s = 0; s < 4; ++s) {
#pragma unroll
            for (int n = 0; n < 4; ++n) {
                const int tok = n * 16 + l15;
                const uint_t byte = (uint_t)(tok * 256)
                    + (((uint_t)((s * 32 + lhi * 8) * 2)) ^ ((uint_t)((tok & 7) << 4)));
                short8 kb = *(const short8*)(kbuf + byte);
                sacc[n] = __builtin_amdgcn_mfma_f32_16x16x32_bf16(qf[s], kb, sacc[n], 0, 0, 0);
            }
        }

        // ---- softmax with deferred max
        const bool diag = (jb == qt);
        float pv[4][4];
#pragma unroll
        for (int n = 0; n < 4; ++n)
#pragma unroll
            for (int j = 0; j < 4; ++j) {
                float x = sacc[n][j];
                if (diag) {
                    const int tok = jb * 64 + n * 16 + l15;
                    const int qg  = qt * 64 + w * 16 + lhi * 4 + j;
                    if (tok > qg) x = -1e30f;
                }
                pv[n][j] = x;
            }
#pragma unroll
        for (int j = 0; j < 4; ++j) {
            float lmax = fmaxf(fmaxf(pv[0][j], pv[1][j]), fmaxf(pv[2][j], pv[3][j]));
            if (__any(lmax > m_run[j] + RESCALE_THR)) {
                float mt = lmax;
#pragma unroll
                for (int off = 1; off < 16; off <<= 1)
                    mt = fmaxf(mt, __shfl_xor(mt, off));
                const float mn = fmaxf(m_run[j], mt);
                const float alpha = __expf(m_run[j] - mn);
                m_run[j] = mn;
                l_part[j] *= alpha;
#pragma unroll
                for (int n2 = 0; n2 < 8; ++n2) acc[n2][j] *= alpha;
            }
            float ls = 0.f;
#pragma unroll
            for (int n = 0; n < 4; ++n) {
                float p = __expf(pv[n][j] - m_run[j]);
                pv[n][j] = p;
                ls += p;
            }
            l_part[j] += ls;
        }

        // ---- P -> per-wave LDS (A-fragment relayout); same-wave lgkmcnt
        char* pb = sP[w];
#pragma unroll
        for (int n = 0; n < 4; ++n)
#pragma unroll
            for (int j = 0; j < 4; ++j) {
                const int r = lhi * 4 + j;
                const uint_t byte = (uint_t)(r * 128)
                    + (((uint_t)((n * 16 + l15) * 2)) ^ ((uint_t)((r & 7) << 4)));
                *(ushort_t*)(pb + byte) = f2bf(pv[n][j]);
            }

        // ---- O += P V
#pragma unroll
        for (int s2 = 0; s2 < 2; ++s2) {
            const uint_t pbyte = (uint_t)(l15 * 128)
                + (((uint_t)((s2 * 32 + lhi * 8) * 2)) ^ ((uint_t)((l15 & 7) << 4)));
            short8 pa = *(const short8*)(pb + pbyte);
#pragma unroll
            for (int n2 = 0; n2 < 8; ++n2) {
                const int dim = n2 * 16 + l15;
                const uint_t vbyte = (uint_t)(dim * 128)
                    + (((uint_t)((s2 * 32 + lhi * 8) * 2)) ^ ((uint_t)((dim & 7) << 4)));
                short8 vbf = *(const short8*)(vbuf + vbyte);
                acc[n2] = __builtin_amdgcn_mfma_f32_16x16x32_bf16(pa, vbf, acc[n2], 0, 0, 0);
            }
        }

        if (pf) {
            // all waves done reading buf[cur]; next iter's STAGE may overwrite
            __builtin_amdgcn_sched_barrier(0);
            __builtin_amdgcn_s_barrier();
        }
    }

    // ---- epilogue: reduce per-lane l across 16-lane row group, store
#pragma unroll
    for (int j = 0; j < 4; ++j) {
        float lsum = l_part[j];
#pragma unroll
        for (int off = 1; off < 16; off <<= 1)
            lsum += __shfl_xor(lsum, off);
        const float inv = 1.0f / lsum;
        const int qg = qt * 64 + w * 16 + lhi * 4 + j;
        float* dst = out + (size_t)qg * Q_STRIDE + h * HEAD_DIM;
#pragma unroll
        for (int n2 = 0; n2 < 8; ++n2)
            dst[n2 * 16 + l15] = acc[n2][j] * inv;
    }
}

extern "C" void kernel_launch(void* const* d_in, const int* in_sizes, int n_in,
                              void* d_out, int out_size, void* d_ws, size_t ws_size,
                              hipStream_t stream) {
    const float* q   = (const float*)d_in[0];
    // d_in[1] (k) and d_in[2] (v) are dead under the reference's causal mask.
    const float* kvc = (const float*)d_in[3];
    const int*   bt  = (const int*)d_in[4];
    float* out = (float*)d_out;
    char*  wsb = (char*)d_ws;
    prep_kv<<<dim3(128), dim3(256), 0, stream>>>(kvc, bt, wsb);
    attn_main<<<dim3(512), dim3(256), 0, stream>>>(q, wsb, out);
}